// Round 2
// baseline (1949.807 us; speedup 1.0000x reference)
//
#include <hip/hip_runtime.h>
#include <math.h>

// Problem constants
#define B_   8
#define H_   128
#define W_   128
#define C_   256
#define WS_  8
#define SS_  4
#define NH_  8
#define HD_  32
#define MROWS 131072   // B * H * W tokens

typedef short bf16x8 __attribute__((ext_vector_type(8)));
typedef float f32x4  __attribute__((ext_vector_type(4)));

__device__ __forceinline__ unsigned short f2bf(float f) {
    unsigned int u = __float_as_uint(f);
    u += 0x7fffu + ((u >> 16) & 1u);          // round-to-nearest-even
    return (unsigned short)(u >> 16);
}
__device__ __forceinline__ float bf2f(unsigned short s) {
    return __uint_as_float(((unsigned int)s) << 16);
}

// ---------------------------------------------------------------------------
// fp32 -> bf16 weight conversion (4 elements / thread)
// ---------------------------------------------------------------------------
__global__ __launch_bounds__(256) void cvt4(const float* __restrict__ s,
                                            unsigned short* __restrict__ d, int n) {
    const int i = (blockIdx.x * 256 + threadIdx.x) * 4;
    if (i >= n) return;
    const float4 v = *(const float4*)(s + i);
    ushort4 o;
    o.x = f2bf(v.x); o.y = f2bf(v.y); o.z = f2bf(v.z); o.w = f2bf(v.w);
    *(ushort4*)(d + i) = o;
}

// ---------------------------------------------------------------------------
// LayerNorm: one wave per token, 4 channels/lane. fp32 in -> bf16 out.
// SHIFT=1: destination row is (shifted frame, window-partition) layout;
// gathers source through the cyclic shift.
// ---------------------------------------------------------------------------
template<int SHIFT>
__global__ __launch_bounds__(256) void ln_kernel(const float* __restrict__ in,
                                                 const float* __restrict__ g,
                                                 const float* __restrict__ b,
                                                 unsigned short* __restrict__ out) {
    const int wid  = threadIdx.x >> 6;
    const int lane = threadIdx.x & 63;
    const int row  = blockIdx.x * 4 + wid;   // destination row

    int src;
    if (SHIFT) {
        const int bimg = row >> 14;
        const int rem  = row & 16383;
        const int win  = rem >> 6;
        const int tok  = rem & 63;
        const int hp = (win >> 4) * 8 + (tok >> 3);
        const int wp = (win & 15) * 8 + (tok & 7);
        const int ho = (hp + SS_) & (H_ - 1);
        const int wo = (wp + SS_) & (W_ - 1);
        src = (bimg << 14) + ho * W_ + wo;
    } else {
        src = row;
    }

    const float4 v = ((const float4*)(in + (size_t)src * C_))[lane];
    float s  = v.x + v.y + v.z + v.w;
    float ss = v.x*v.x + v.y*v.y + v.z*v.z + v.w*v.w;
#pragma unroll
    for (int o = 1; o < 64; o <<= 1) {
        s  += __shfl_xor(s,  o, 64);
        ss += __shfl_xor(ss, o, 64);
    }
    const float mean = s * (1.0f / C_);
    const float var  = ss * (1.0f / C_) - mean * mean;
    const float rstd = rsqrtf(var + 1e-5f);

    const float4 gg = ((const float4*)g)[lane];
    const float4 bb = ((const float4*)b)[lane];
    ushort4 o4;
    o4.x = f2bf((v.x - mean) * rstd * gg.x + bb.x);
    o4.y = f2bf((v.y - mean) * rstd * gg.y + bb.y);
    o4.z = f2bf((v.z - mean) * rstd * gg.z + bb.z);
    o4.w = f2bf((v.w - mean) * rstd * gg.w + bb.w);
    *(ushort4*)(out + (size_t)row * C_ + lane * 4) = o4;
}

// ---------------------------------------------------------------------------
// bf16 MFMA GEMM:  C[m,n] = sum_k A[m,k]*Bw[n,k] + bias[n]
// A: MxK bf16 row-major, Bw: NxK bf16 row-major. 256 thr = 4 waves (2x2),
// block tile 128x64, wave tile 64x32 (4x2 fragments of 16x16, K-step 32).
// No LDS: fragments loaded directly from global (L1/L2-served).
// EPI: 0 bias->bf16 | 1 bias+unshift-scatter+residual(fp32 x)->fp32
//      2 bias+GELU->bf16 | 3 bias+in-place residual fp32
// ---------------------------------------------------------------------------
template<int EPI>
__global__ __launch_bounds__(256) void mgemm(const unsigned short* __restrict__ A,
                                             const unsigned short* __restrict__ Bw,
                                             const float* __restrict__ bias,
                                             void* __restrict__ Cout,
                                             const float* __restrict__ resid,
                                             int M, int N, int K) {
    const int t    = threadIdx.x;
    const int wave = t >> 6, lane = t & 63;
    const int wr   = wave >> 1, wc = wave & 1;
    const int m0   = blockIdx.y * 128 + wr * 64;
    const int n0   = blockIdx.x * 64  + wc * 32;
    const int fr   = lane & 15;          // fragment row (A) / col (B)
    const int kh   = (lane >> 4) * 8;    // k sub-offset

    const unsigned short* Ap = A  + (size_t)(m0 + fr) * K + kh;
    const unsigned short* Bp = Bw + (size_t)(n0 + fr) * K + kh;

    f32x4 acc[4][2] = {};

    for (int k0 = 0; k0 < K; k0 += 32) {
        bf16x8 a[4], b[2];
#pragma unroll
        for (int mi = 0; mi < 4; ++mi)
            a[mi] = *(const bf16x8*)(Ap + (size_t)mi * 16 * K + k0);
#pragma unroll
        for (int ni = 0; ni < 2; ++ni)
            b[ni] = *(const bf16x8*)(Bp + (size_t)ni * 16 * K + k0);
#pragma unroll
        for (int mi = 0; mi < 4; ++mi)
#pragma unroll
            for (int ni = 0; ni < 2; ++ni)
                acc[mi][ni] = __builtin_amdgcn_mfma_f32_16x16x32_bf16(
                    a[mi], b[ni], acc[mi][ni], 0, 0, 0);
    }

    // C/D layout: col = lane&15, row = (lane>>4)*4 + reg   [m89/m91 verified]
    float bv[2];
    bv[0] = bias[n0 + fr];
    bv[1] = bias[n0 + 16 + fr];

#pragma unroll
    for (int mi = 0; mi < 4; ++mi) {
#pragma unroll
        for (int ni = 0; ni < 2; ++ni) {
            const int col = n0 + ni * 16 + fr;
#pragma unroll
            for (int j = 0; j < 4; ++j) {
                const int row = m0 + mi * 16 + (lane >> 4) * 4 + j;
                float v = acc[mi][ni][j] + bv[ni];
                if (EPI == 2)
                    v = 0.5f * v * (1.0f + erff(v * 0.70710678118654752f));
                if (EPI == 0 || EPI == 2) {
                    ((unsigned short*)Cout)[(size_t)row * N + col] = f2bf(v);
                } else if (EPI == 3) {
                    float* o = (float*)Cout;
                    const size_t idx = (size_t)row * N + col;
                    o[idx] = v + resid[idx];
                } else { // EPI == 1: window-reverse + unshift scatter + residual
                    const int bimg = row >> 14;
                    const int rem  = row & 16383;
                    const int win  = rem >> 6;
                    const int tok  = rem & 63;
                    const int hp = (win >> 4) * 8 + (tok >> 3);
                    const int wp = (win & 15) * 8 + (tok & 7);
                    const int ho = (hp + SS_) & (H_ - 1);
                    const int wo = (wp + SS_) & (W_ - 1);
                    const size_t dst = ((size_t)(bimg << 14) + ho * W_ + wo) * C_ + col;
                    ((float*)Cout)[dst] = v + resid[dst];
                }
            }
        }
    }
}

// ---------------------------------------------------------------------------
// Windowed attention, one block (256 thr) per (window, head). bf16 in/out,
// fp32 math in LDS. Rel-pos bias + shift mask computed analytically.
// ---------------------------------------------------------------------------
__device__ __forceinline__ int grp_(int p) { return p < (H_ - WS_) ? 0 : (p < (H_ - SS_) ? 1 : 2); }

__device__ __forceinline__ void unp8(uint4 u, float* o) {
    o[0] = __uint_as_float(u.x << 16); o[1] = __uint_as_float(u.x & 0xffff0000u);
    o[2] = __uint_as_float(u.y << 16); o[3] = __uint_as_float(u.y & 0xffff0000u);
    o[4] = __uint_as_float(u.z << 16); o[5] = __uint_as_float(u.z & 0xffff0000u);
    o[6] = __uint_as_float(u.w << 16); o[7] = __uint_as_float(u.w & 0xffff0000u);
}

__global__ __launch_bounds__(256) void attn_kernel(const unsigned short* __restrict__ qkv,
                                                   const float* __restrict__ rpb,
                                                   unsigned short* __restrict__ out) {
    __shared__ float q[64][36], k[64][36], vv[64][36];
    __shared__ float S[64][65];

    const int head = blockIdx.x & 7;
    const int win  = blockIdx.x >> 3;
    const int t    = threadIdx.x;
    const float qscale = 0.17677669529663687f;   // 1/sqrt(32)

    {
        const int tok = t >> 2;
        const int dv  = (t & 3) * 8;
        const size_t base = ((size_t)win * 64 + tok) * 768 + head * HD_ + dv;
        float f[8];
        unp8(*(const uint4*)(qkv + base), f);
#pragma unroll
        for (int j = 0; j < 8; ++j) q[tok][dv + j] = f[j] * qscale;
        unp8(*(const uint4*)(qkv + base + 256), f);
#pragma unroll
        for (int j = 0; j < 8; ++j) k[tok][dv + j] = f[j];
        unp8(*(const uint4*)(qkv + base + 512), f);
#pragma unroll
        for (int j = 0; j < 8; ++j) vv[tok][dv + j] = f[j];
    }
    __syncthreads();

    const int wim = win & 255;
    const int whb = (wim >> 4) * 8;
    const int wwb = (wim & 15) * 8;

#pragma unroll
    for (int e = 0; e < 16; ++e) {
        const int idx = e * 256 + t;
        const int i = idx >> 6, j = idx & 63;
        float dot = 0.0f;
        const float4* qi = (const float4*)q[i];
        const float4* kj = (const float4*)k[j];
#pragma unroll
        for (int d = 0; d < 8; ++d) {
            const float4 a = qi[d], b = kj[d];
            dot += a.x*b.x + a.y*b.y + a.z*b.z + a.w*b.w;
        }
        const int yi = i >> 3, xi = i & 7, yj = j >> 3, xj = j & 7;
        dot += rpb[((yi - yj + 7) * 15 + (xi - xj + 7)) * NH_ + head];
        const int gi = grp_(whb + yi) * 3 + grp_(wwb + xi);
        const int gj = grp_(whb + yj) * 3 + grp_(wwb + xj);
        if (gi != gj) dot -= 100.0f;
        S[i][j] = dot;
    }
    __syncthreads();

    const int wid = t >> 6, lane = t & 63;
    for (int rr = 0; rr < 16; ++rr) {
        const int row = wid * 16 + rr;
        const float vS = S[row][lane];
        float mx = vS;
#pragma unroll
        for (int o = 1; o < 64; o <<= 1) mx = fmaxf(mx, __shfl_xor(mx, o, 64));
        const float e = __expf(vS - mx);
        float sm = e;
#pragma unroll
        for (int o = 1; o < 64; o <<= 1) sm += __shfl_xor(sm, o, 64);
        S[row][lane] = e / sm;
    }
    __syncthreads();

    const int i  = t >> 2;
    const int d0 = (t & 3) * 8;
    float o[8] = {};
    for (int j = 0; j < 64; ++j) {
        const float p = S[i][j];
        const float4 v0 = *(const float4*)&vv[j][d0];
        const float4 v1 = *(const float4*)&vv[j][d0 + 4];
        o[0] = fmaf(p, v0.x, o[0]); o[1] = fmaf(p, v0.y, o[1]);
        o[2] = fmaf(p, v0.z, o[2]); o[3] = fmaf(p, v0.w, o[3]);
        o[4] = fmaf(p, v1.x, o[4]); o[5] = fmaf(p, v1.y, o[5]);
        o[6] = fmaf(p, v1.z, o[6]); o[7] = fmaf(p, v1.w, o[7]);
    }
    ushort u8[8];
#pragma unroll
    for (int j = 0; j < 8; ++j) u8[j] = f2bf(o[j]);
    const size_t ob = ((size_t)win * 64 + i) * C_ + head * HD_ + d0;
    *(uint4*)(out + ob) = *(const uint4*)u8;
}

// ---------------------------------------------------------------------------
extern "C" void kernel_launch(void* const* d_in, const int* in_sizes, int n_in,
                              void* d_out, int out_size, void* d_ws, size_t ws_size,
                              hipStream_t stream) {
    const float* x      = (const float*)d_in[0];
    const float* n1g    = (const float*)d_in[1];
    const float* n1b    = (const float*)d_in[2];
    const float* qkv_w  = (const float*)d_in[3];
    const float* qkv_b  = (const float*)d_in[4];
    const float* rpb    = (const float*)d_in[5];
    const float* proj_w = (const float*)d_in[6];
    const float* proj_b = (const float*)d_in[7];
    const float* n2g    = (const float*)d_in[8];
    const float* n2b    = (const float*)d_in[9];
    const float* fc1_w  = (const float*)d_in[10];
    const float* fc1_b  = (const float*)d_in[11];
    const float* fc2_w  = (const float*)d_in[12];
    const float* fc2_b  = (const float*)d_in[13];
    float* out = (float*)d_out;

    // workspace (bf16 elements). Peak use = 2 MB + 64 MB + 256 MB = 322 MB.
    unsigned short* wq  = (unsigned short*)d_ws;         // weights bf16 (1.5 MB)
    unsigned short* rA  = wq + (1u << 20);               // 64 MB region: xw / attn_o / ln2o
    unsigned short* rB  = rA + 33554432u;                // 256 MB region: qkv / mlp1

    unsigned short* qkv_wb  = wq;
    unsigned short* proj_wb = wq + 196608;
    unsigned short* fc1_wb  = wq + 262144;
    unsigned short* fc2_wb  = wq + 524288;

    // 0. weights -> bf16
    cvt4<<<192, 256, 0, stream>>>(qkv_w,  qkv_wb,  196608);
    cvt4<<<64,  256, 0, stream>>>(proj_w, proj_wb, 65536);
    cvt4<<<256, 256, 0, stream>>>(fc1_w,  fc1_wb,  262144);
    cvt4<<<256, 256, 0, stream>>>(fc2_w,  fc2_wb,  262144);

    // 1. LN1 + cyclic shift + window partition  (x -> rA as bf16)
    ln_kernel<1><<<MROWS / 4, 256, 0, stream>>>(x, n1g, n1b, rA);
    // 2. QKV projection (rA -> rB bf16)
    mgemm<0><<<dim3(768 / 64, MROWS / 128), 256, 0, stream>>>(
        rA, qkv_wb, qkv_b, rB, nullptr, MROWS, 768, 256);
    // 3. windowed attention (rB -> rA bf16)
    attn_kernel<<<2048 * NH_, 256, 0, stream>>>(rB, rpb, rA);
    // 4. proj + window-reverse/unshift scatter + shortcut residual -> d_out fp32
    mgemm<1><<<dim3(256 / 64, MROWS / 128), 256, 0, stream>>>(
        rA, proj_wb, proj_b, out, x, MROWS, 256, 256);
    // 5. LN2 (out -> rA bf16)
    ln_kernel<0><<<MROWS / 4, 256, 0, stream>>>(out, n2g, n2b, rA);
    // 6. FC1 + exact GELU (rA -> rB bf16)
    mgemm<2><<<dim3(1024 / 64, MROWS / 128), 256, 0, stream>>>(
        rA, fc1_wb, fc1_b, rB, nullptr, MROWS, 1024, 256);
    // 7. FC2 + residual (in-place on d_out fp32)
    mgemm<3><<<dim3(256 / 64, MROWS / 128), 256, 0, stream>>>(
        rB, fc2_wb, fc2_b, out, out, MROWS, 256, 1024);
}

// Round 3
// 684.261 us; speedup vs baseline: 2.8495x; 2.8495x over previous
//
#include <hip/hip_runtime.h>
#include <math.h>

// Problem constants
#define B_   8
#define H_   128
#define W_   128
#define C_   256
#define WS_  8
#define SS_  4
#define NH_  8
#define HD_  32
#define MROWS 131072   // B * H * W tokens

typedef short bf16x8 __attribute__((ext_vector_type(8)));
typedef float f32x4  __attribute__((ext_vector_type(4)));

__device__ __forceinline__ unsigned short f2bf(float f) {
    unsigned int u = __float_as_uint(f);
    u += 0x7fffu + ((u >> 16) & 1u);          // round-to-nearest-even
    return (unsigned short)(u >> 16);
}

// async global->LDS, 16 bytes per lane; lds dest = wave-uniform base + lane*16
__device__ __forceinline__ void gload16(const unsigned short* g, unsigned short* l) {
    __builtin_amdgcn_global_load_lds(
        (const __attribute__((address_space(1))) unsigned int*)(const void*)g,
        (__attribute__((address_space(3))) unsigned int*)(void*)l, 16, 0, 0);
}

// ---------------------------------------------------------------------------
// fp32 -> bf16 weight conversion
// ---------------------------------------------------------------------------
__global__ __launch_bounds__(256) void cvt4(const float* __restrict__ s,
                                            unsigned short* __restrict__ d, int n) {
    const int i = (blockIdx.x * 256 + threadIdx.x) * 4;
    if (i >= n) return;
    const float4 v = *(const float4*)(s + i);
    ushort4 o;
    o.x = f2bf(v.x); o.y = f2bf(v.y); o.z = f2bf(v.z); o.w = f2bf(v.w);
    *(ushort4*)(d + i) = o;
}

// ---------------------------------------------------------------------------
// LayerNorm: one wave per token, 4 channels/lane. fp32 in -> bf16 out.
// SHIFT=1: dest row is (shifted frame, window-partition) layout.
// ---------------------------------------------------------------------------
template<int SHIFT>
__global__ __launch_bounds__(256) void ln_kernel(const float* __restrict__ in,
                                                 const float* __restrict__ g,
                                                 const float* __restrict__ b,
                                                 unsigned short* __restrict__ out) {
    const int wid  = threadIdx.x >> 6;
    const int lane = threadIdx.x & 63;
    const int row  = blockIdx.x * 4 + wid;

    int src;
    if (SHIFT) {
        const int bimg = row >> 14;
        const int rem  = row & 16383;
        const int win  = rem >> 6;
        const int tok  = rem & 63;
        const int hp = (win >> 4) * 8 + (tok >> 3);
        const int wp = (win & 15) * 8 + (tok & 7);
        const int ho = (hp + SS_) & (H_ - 1);
        const int wo = (wp + SS_) & (W_ - 1);
        src = (bimg << 14) + ho * W_ + wo;
    } else {
        src = row;
    }

    const float4 v = ((const float4*)(in + (size_t)src * C_))[lane];
    float s  = v.x + v.y + v.z + v.w;
    float ss = v.x*v.x + v.y*v.y + v.z*v.z + v.w*v.w;
#pragma unroll
    for (int o = 1; o < 64; o <<= 1) {
        s  += __shfl_xor(s,  o, 64);
        ss += __shfl_xor(ss, o, 64);
    }
    const float mean = s * (1.0f / C_);
    const float var  = ss * (1.0f / C_) - mean * mean;
    const float rstd = rsqrtf(var + 1e-5f);

    const float4 gg = ((const float4*)g)[lane];
    const float4 bb = ((const float4*)b)[lane];
    ushort4 o4;
    o4.x = f2bf((v.x - mean) * rstd * gg.x + bb.x);
    o4.y = f2bf((v.y - mean) * rstd * gg.y + bb.y);
    o4.z = f2bf((v.z - mean) * rstd * gg.z + bb.z);
    o4.w = f2bf((v.w - mean) * rstd * gg.w + bb.w);
    *(ushort4*)(out + (size_t)row * C_ + lane * 4) = o4;
}

// ---------------------------------------------------------------------------
// bf16 MFMA GEMM, m97 structure: 128x128 tile, BK=64, LDS staging via
// global_load_lds (16B), 4 waves (2x2), wave tile 64x64 (4x4 frags 16x16x32).
// A: MxK bf16 row-major, Bw: NxK bf16 row-major.
// EPI: 0 bias->bf16 | 1 bias+unshift-scatter+residual(fp32)->fp32
//      2 bias+GELU->bf16 | 3 bias+in-place residual fp32
// ---------------------------------------------------------------------------
template<int EPI>
__global__ __launch_bounds__(256) void mgemm(const unsigned short* __restrict__ A,
                                             const unsigned short* __restrict__ Bw,
                                             const float* __restrict__ bias,
                                             void* __restrict__ Cout,
                                             const float* __restrict__ resid,
                                             int M, int N, int K) {
    __shared__ unsigned short As[128 * 64];
    __shared__ unsigned short Bs[128 * 64];

    const int t    = threadIdx.x;
    const int wave = t >> 6, lane = t & 63;
    const int fr   = lane & 15, h = lane >> 4;
    const int wr   = wave >> 1, wc = wave & 1;
    const int m0   = blockIdx.y * 128;
    const int n0   = blockIdx.x * 128;
    const int moff = wr * 64, noff = wc * 64;

    const unsigned short* Ab = A  + (size_t)m0 * K;
    const unsigned short* Bb = Bw + (size_t)n0 * K;
    const int srow = t >> 3;            // 0..31 (per issue +32)
    const int scol = (t & 7) * 8;       // 0,8,...,56

    f32x4 acc[4][4] = {};

    for (int kt = 0; kt < K; kt += 64) {
#pragma unroll
        for (int i = 0; i < 4; ++i) {
            gload16(Ab + (size_t)(i * 32 + srow) * K + kt + scol,
                    &As[(i * 256 + wave * 64) * 8]);
            gload16(Bb + (size_t)(i * 32 + srow) * K + kt + scol,
                    &Bs[(i * 256 + wave * 64) * 8]);
        }
        __syncthreads();
#pragma unroll
        for (int ks = 0; ks < 2; ++ks) {
            bf16x8 a[4], b[4];
#pragma unroll
            for (int mi = 0; mi < 4; ++mi)
                a[mi] = *(const bf16x8*)&As[(moff + mi * 16 + fr) * 64 + ks * 32 + h * 8];
#pragma unroll
            for (int nj = 0; nj < 4; ++nj)
                b[nj] = *(const bf16x8*)&Bs[(noff + nj * 16 + fr) * 64 + ks * 32 + h * 8];
#pragma unroll
            for (int mi = 0; mi < 4; ++mi)
#pragma unroll
                for (int nj = 0; nj < 4; ++nj)
                    acc[mi][nj] = __builtin_amdgcn_mfma_f32_16x16x32_bf16(
                        a[mi], b[nj], acc[mi][nj], 0, 0, 0);
        }
        __syncthreads();
    }

    float bv[4];
#pragma unroll
    for (int nj = 0; nj < 4; ++nj) bv[nj] = bias[n0 + noff + nj * 16 + fr];

#pragma unroll
    for (int mi = 0; mi < 4; ++mi) {
#pragma unroll
        for (int nj = 0; nj < 4; ++nj) {
            const int col = n0 + noff + nj * 16 + fr;
#pragma unroll
            for (int j = 0; j < 4; ++j) {
                const int row = m0 + moff + mi * 16 + h * 4 + j;
                float v = acc[mi][nj][j] + bv[nj];
                if (EPI == 2)
                    v = 0.5f * v * (1.0f + erff(v * 0.70710678118654752f));
                if (EPI == 0 || EPI == 2) {
                    ((unsigned short*)Cout)[(size_t)row * N + col] = f2bf(v);
                } else if (EPI == 3) {
                    float* o = (float*)Cout;
                    const size_t idx = (size_t)row * N + col;
                    o[idx] = v + resid[idx];
                } else { // EPI == 1
                    const int bimg = row >> 14;
                    const int rem  = row & 16383;
                    const int win  = rem >> 6;
                    const int tok  = rem & 63;
                    const int hp = (win >> 4) * 8 + (tok >> 3);
                    const int wp = (win & 15) * 8 + (tok & 7);
                    const int ho = (hp + SS_) & (H_ - 1);
                    const int wo = (wp + SS_) & (W_ - 1);
                    const size_t dst = ((size_t)(bimg << 14) + ho * W_ + wo) * C_ + col;
                    ((float*)Cout)[dst] = v + resid[dst];
                }
            }
        }
    }
}

// ---------------------------------------------------------------------------
// MFMA windowed attention. Block = 256 thr = 4 waves; all waves share one
// head (rpb slice in LDS), each wave owns one window. Swapped QK^T
// (S^T = mfma(K,Q)) -> softmax reduce = 16 local + 2 shfl_xor. P and
// transposed V staged per-wave in LDS for the PV MFMAs.
// ---------------------------------------------------------------------------
__device__ __forceinline__ int grp_(int p) { return p < (H_ - WS_) ? 0 : (p < (H_ - SS_) ? 1 : 2); }

__global__ __launch_bounds__(256) void attn_kernel(const unsigned short* __restrict__ qkv,
                                                   const float* __restrict__ rpb,
                                                   unsigned short* __restrict__ out) {
    __shared__ unsigned short P [4][64 * 72];
    __shared__ unsigned short Vt[4][32 * 72];
    __shared__ float rpb_s[232];

    const int t    = threadIdx.x;
    const int wid  = t >> 6, lane = t & 63;
    const int head = blockIdx.x & 7;
    const int win  = (blockIdx.x >> 3) * 4 + wid;
    const int fr   = lane & 15, h = lane >> 4;

    if (t < 225) rpb_s[t] = rpb[t * 8 + head];
    __syncthreads();

    const size_t qbase = (size_t)win * 64 * 768 + head * HD_;

    // fragments: A = K rows, B = Q rows (both k-contiguous in global)
    bf16x8 ak[4], bq[4];
#pragma unroll
    for (int ki = 0; ki < 4; ++ki)
        ak[ki] = *(const bf16x8*)&qkv[qbase + (size_t)(ki * 16 + fr) * 768 + 256 + h * 8];
#pragma unroll
    for (int qj = 0; qj < 4; ++qj)
        bq[qj] = *(const bf16x8*)&qkv[qbase + (size_t)(qj * 16 + fr) * 768 + h * 8];

    // V transpose into LDS: lane loads V row `lane`, scatters into Vt[d][lane]
    {
        const unsigned short* vrow = &qkv[qbase + (size_t)lane * 768 + 512];
#pragma unroll
        for (int dv = 0; dv < 32; dv += 8) {
            bf16x8 v8 = *(const bf16x8*)&vrow[dv];
#pragma unroll
            for (int j = 0; j < 8; ++j)
                Vt[wid][(dv + j) * 72 + lane] = ((unsigned short*)&v8)[j];
        }
    }

    // S^T = K · Q^T : st[ki][qj], C/D layout: q = col = lane&15, k-row = h*4+reg
    f32x4 st[4][4] = {};
#pragma unroll
    for (int ki = 0; ki < 4; ++ki)
#pragma unroll
        for (int qj = 0; qj < 4; ++qj)
            st[ki][qj] = __builtin_amdgcn_mfma_f32_16x16x32_bf16(ak[ki], bq[qj], st[ki][qj], 0, 0, 0);

    const int wim = win & 255;
    const int whb = (wim >> 4) * 8, wwb = (wim & 15) * 8;
    const float qscale = 0.17677669529663687f;   // 1/sqrt(32)

#pragma unroll
    for (int qj = 0; qj < 4; ++qj) {
        const int q  = qj * 16 + fr;
        const int yq = q >> 3, xq = q & 7;
        const int gq = grp_(whb + yq) * 3 + grp_(wwb + xq);
        float s[16];
#pragma unroll
        for (int ki = 0; ki < 4; ++ki)
#pragma unroll
            for (int r = 0; r < 4; ++r) {
                const int k  = ki * 16 + h * 4 + r;
                const int yk = k >> 3, xk = k & 7;
                const int gk = grp_(whb + yk) * 3 + grp_(wwb + xk);
                float v = fmaf(st[ki][qj][r], qscale,
                               rpb_s[(yq - yk + 7) * 15 + (xq - xk + 7)]);
                if (gk != gq) v -= 100.0f;
                s[ki * 4 + r] = v;
            }
        float m = s[0];
#pragma unroll
        for (int i = 1; i < 16; ++i) m = fmaxf(m, s[i]);
        m = fmaxf(m, __shfl_xor(m, 16, 64));
        m = fmaxf(m, __shfl_xor(m, 32, 64));
        float sum = 0.0f;
#pragma unroll
        for (int i = 0; i < 16; ++i) { s[i] = __expf(s[i] - m); sum += s[i]; }
        sum += __shfl_xor(sum, 16, 64);
        sum += __shfl_xor(sum, 32, 64);
        const float rinv = __builtin_amdgcn_rcpf(sum);
#pragma unroll
        for (int ki = 0; ki < 4; ++ki)
#pragma unroll
            for (int rp = 0; rp < 4; rp += 2) {
                const unsigned int lo = f2bf(s[ki * 4 + rp]     * rinv);
                const unsigned int hi = f2bf(s[ki * 4 + rp + 1] * rinv);
                *(unsigned int*)&P[wid][q * 72 + ki * 16 + h * 4 + rp] = lo | (hi << 16);
            }
    }
    // per-wave LDS region: in-wave RAW ordering handled by compiler waitcnts

    // O = P · V : A-frags from P (row-major), B-frags from Vt (V^T rows)
    f32x4 oacc[4][2] = {};
#pragma unroll
    for (int ks = 0; ks < 2; ++ks) {
        bf16x8 pa[4], vb[2];
#pragma unroll
        for (int qi = 0; qi < 4; ++qi)
            pa[qi] = *(const bf16x8*)&P[wid][(qi * 16 + fr) * 72 + ks * 32 + h * 8];
#pragma unroll
        for (int nj = 0; nj < 2; ++nj)
            vb[nj] = *(const bf16x8*)&Vt[wid][(nj * 16 + fr) * 72 + ks * 32 + h * 8];
#pragma unroll
        for (int qi = 0; qi < 4; ++qi)
#pragma unroll
            for (int nj = 0; nj < 2; ++nj)
                oacc[qi][nj] = __builtin_amdgcn_mfma_f32_16x16x32_bf16(pa[qi], vb[nj], oacc[qi][nj], 0, 0, 0);
    }

#pragma unroll
    for (int qi = 0; qi < 4; ++qi)
#pragma unroll
        for (int nj = 0; nj < 2; ++nj)
#pragma unroll
            for (int r = 0; r < 4; ++r) {
                const int q = qi * 16 + h * 4 + r;
                const int d = nj * 16 + fr;
                out[((size_t)win * 64 + q) * C_ + head * HD_ + d] = f2bf(oacc[qi][nj][r]);
            }
}

// ---------------------------------------------------------------------------
extern "C" void kernel_launch(void* const* d_in, const int* in_sizes, int n_in,
                              void* d_out, int out_size, void* d_ws, size_t ws_size,
                              hipStream_t stream) {
    const float* x      = (const float*)d_in[0];
    const float* n1g    = (const float*)d_in[1];
    const float* n1b    = (const float*)d_in[2];
    const float* qkv_w  = (const float*)d_in[3];
    const float* qkv_b  = (const float*)d_in[4];
    const float* rpb    = (const float*)d_in[5];
    const float* proj_w = (const float*)d_in[6];
    const float* proj_b = (const float*)d_in[7];
    const float* n2g    = (const float*)d_in[8];
    const float* n2b    = (const float*)d_in[9];
    const float* fc1_w  = (const float*)d_in[10];
    const float* fc1_b  = (const float*)d_in[11];
    const float* fc2_w  = (const float*)d_in[12];
    const float* fc2_b  = (const float*)d_in[13];
    float* out = (float*)d_out;

    // workspace (bf16 elements). Peak = 2 MB + 64 MB + 256 MB = 322 MB.
    unsigned short* wq  = (unsigned short*)d_ws;         // weights bf16
    unsigned short* rA  = wq + (1u << 20);               // 64 MB region
    unsigned short* rB  = rA + 33554432u;                // 256 MB region

    unsigned short* qkv_wb  = wq;
    unsigned short* proj_wb = wq + 196608;
    unsigned short* fc1_wb  = wq + 262144;
    unsigned short* fc2_wb  = wq + 524288;

    cvt4<<<192, 256, 0, stream>>>(qkv_w,  qkv_wb,  196608);
    cvt4<<<64,  256, 0, stream>>>(proj_w, proj_wb, 65536);
    cvt4<<<256, 256, 0, stream>>>(fc1_w,  fc1_wb,  262144);
    cvt4<<<256, 256, 0, stream>>>(fc2_w,  fc2_wb,  262144);

    // 1. LN1 + cyclic shift + window partition  (x -> rA bf16)
    ln_kernel<1><<<MROWS / 4, 256, 0, stream>>>(x, n1g, n1b, rA);
    // 2. QKV projection (rA -> rB bf16)
    mgemm<0><<<dim3(768 / 128, MROWS / 128), 256, 0, stream>>>(
        rA, qkv_wb, qkv_b, rB, nullptr, MROWS, 768, 256);
    // 3. windowed attention (rB -> rA bf16)
    attn_kernel<<<(2048 / 4) * NH_, 256, 0, stream>>>(rB, rpb, rA);
    // 4. proj + window-reverse/unshift scatter + residual -> d_out fp32
    mgemm<1><<<dim3(256 / 128, MROWS / 128), 256, 0, stream>>>(
        rA, proj_wb, proj_b, out, x, MROWS, 256, 256);
    // 5. LN2 (out -> rA bf16)
    ln_kernel<0><<<MROWS / 4, 256, 0, stream>>>(out, n2g, n2b, rA);
    // 6. FC1 + exact GELU (rA -> rB bf16)
    mgemm<2><<<dim3(1024 / 128, MROWS / 128), 256, 0, stream>>>(
        rA, fc1_wb, fc1_b, rB, nullptr, MROWS, 1024, 256);
    // 7. FC2 + residual (in-place on d_out fp32)
    mgemm<3><<<dim3(256 / 128, MROWS / 128), 256, 0, stream>>>(
        rB, fc2_wb, fc2_b, out, out, MROWS, 256, 1024);
}